// Round 1
// baseline (973.372 us; speedup 1.0000x reference)
//
#include <hip/hip_runtime.h>
#include <hip/hip_bf16.h>
#include <math.h>

#define BB 4
#define SS 2048
#define DD 512
#define HH 16
#define DHH 32

__device__ __forceinline__ void fma16(float (&acc)[4][4], const float4 a4, const float4 b4) {
    acc[0][0] += a4.x*b4.x; acc[0][1] += a4.x*b4.y; acc[0][2] += a4.x*b4.z; acc[0][3] += a4.x*b4.w;
    acc[1][0] += a4.y*b4.x; acc[1][1] += a4.y*b4.y; acc[1][2] += a4.y*b4.z; acc[1][3] += a4.y*b4.w;
    acc[2][0] += a4.z*b4.x; acc[2][1] += a4.z*b4.y; acc[2][2] += a4.z*b4.z; acc[2][3] += a4.z*b4.w;
    acc[3][0] += a4.w*b4.x; acc[3][1] += a4.w*b4.y; acc[3][2] += a4.w*b4.z; acc[3][3] += a4.w*b4.w;
}

// ---------------- QKV projection: x[8192,512] @ {Wq,Wk,Wv} -> q,k,v [B,H,S,DH] ----------------
__global__ __launch_bounds__(256) void qkv_gemm_k(
    const float* __restrict__ x,
    const float* __restrict__ Wq, const float* __restrict__ bq,
    const float* __restrict__ Wk, const float* __restrict__ bk,
    const float* __restrict__ Wv, const float* __restrict__ bv,
    float* __restrict__ qo, float* __restrict__ ko, float* __restrict__ vo)
{
    __shared__ float As[16][68];   // [k][m], stride 68 keeps float4 16B-aligned, breaks bank collisions
    __shared__ float Bs[16][64];   // [k][n]
    const int t  = threadIdx.x;
    const int nt = blockIdx.x;            // 0..23  (3 matrices x 8 col-tiles)
    const int mt = blockIdx.y;            // 0..127
    const int mat = nt >> 3;
    const int n0 = (nt & 7) << 6;         // col base within matrix, 0..448
    const int m0 = mt << 6;

    const float* __restrict__ W    = (mat == 0) ? Wq : (mat == 1) ? Wk : Wv;
    const float* __restrict__ bias = (mat == 0) ? bq : (mat == 1) ? bk : bv;
    float* __restrict__ out        = (mat == 0) ? qo : (mat == 1) ? ko : vo;

    // A-tile loads: row am = t>>2 (0..63), k-offset ak = (t&3)*4 -> 64B contiguous per lane-quad
    const int am = t >> 2;
    const int ak = (t & 3) << 2;
    const float* xp = x + (size_t)(m0 + am) * DD + ak;

    // B-tile loads: k-row = t>>4 (0..15), 4-col group = (t&15)*4 (stays inside one head's 32-block)
    const int bkr = t >> 4;
    const int bj  = (t & 15) << 2;
    const int hb  = (n0 + bj) >> 5;
    const int dhb = (n0 + bj) & 31;
    const float* wp = W + (size_t)hb * DD * DHH + (size_t)bkr * DHH + dhb;

    const int tm = (t >> 4) << 2;
    const int tn = (t & 15) << 2;
    float acc[4][4] = {{0.f,0.f,0.f,0.f},{0.f,0.f,0.f,0.f},{0.f,0.f,0.f,0.f},{0.f,0.f,0.f,0.f}};

    for (int k0 = 0; k0 < DD; k0 += 16) {
        float4 av  = *(const float4*)(xp + k0);
        float4 bv4 = *(const float4*)(wp + (size_t)k0 * DHH);
        __syncthreads();
        As[ak + 0][am] = av.x;
        As[ak + 1][am] = av.y;
        As[ak + 2][am] = av.z;
        As[ak + 3][am] = av.w;
        *(float4*)&Bs[bkr][bj] = bv4;
        __syncthreads();
        #pragma unroll
        for (int kk = 0; kk < 16; ++kk) {
            float4 a4 = *(const float4*)&As[kk][tm];
            float4 b4 = *(const float4*)&Bs[kk][tn];
            fma16(acc, a4, b4);
        }
    }

    const int h  = (n0 + tn) >> 5;
    const int dh = (n0 + tn) & 31;
    const float4 bb4 = *(const float4*)(bias + h * DHH + dh);
    #pragma unroll
    for (int i = 0; i < 4; ++i) {
        const int m = m0 + tm + i;
        const int b = m >> 11;          // /S
        const int s = m & (SS - 1);
        float4 o;
        o.x = acc[i][0] + bb4.x;
        o.y = acc[i][1] + bb4.y;
        o.z = acc[i][2] + bb4.z;
        o.w = acc[i][3] + bb4.w;
        *(float4*)(out + ((size_t)(b * HH + h) * SS + s) * DHH + dh) = o;
    }
}

// ---------------- Flash attention (fp32), writes concat-head layout [B,S,D] ----------------
__global__ __launch_bounds__(256) void attn_k(
    const float* __restrict__ q, const float* __restrict__ k,
    const float* __restrict__ v, float* __restrict__ mh)
{
    __shared__ float Ks[64][36];   // stride 36 floats: 16B-aligned rows, conflict-free quad reads
    __shared__ float Vs[64][36];
    const int t  = threadIdx.x;
    const int qt = blockIdx.x & 31;     // q-tile (64 rows) within sequence
    const int bh = blockIdx.x >> 5;     // 0..63 (b*H + h)
    const int r  = t >> 2;              // local q row, 0..63 (one row per lane-quad)
    const int qq = t & 3;               // quad member

    const float scale = 0.17677669529663687f;  // 1/sqrt(32)
    float qreg[32];
    {
        const float* qbase = q + ((size_t)bh * SS + (qt << 6) + r) * DHH;
        #pragma unroll
        for (int i = 0; i < 8; ++i) {
            float4 v4 = *(const float4*)(qbase + i * 4);
            qreg[i*4+0] = v4.x * scale;
            qreg[i*4+1] = v4.y * scale;
            qreg[i*4+2] = v4.z * scale;
            qreg[i*4+3] = v4.w * scale;
        }
    }
    float m_run = -INFINITY, l_run = 0.f;
    float acc[32];
    #pragma unroll
    for (int i = 0; i < 32; ++i) acc[i] = 0.f;

    const float* kb = k + (size_t)bh * SS * DHH;
    const float* vb = v + (size_t)bh * SS * DHH;

    for (int kt = 0; kt < SS / 64; ++kt) {
        __syncthreads();
        {
            const float* ktb = kb + ((size_t)kt << 6) * DHH;
            const float* vtb = vb + ((size_t)kt << 6) * DHH;
            #pragma unroll
            for (int f = 0; f < 2; ++f) {
                const int idx = t + (f << 8);        // 0..511
                const int row = idx >> 3;
                const int d4  = (idx & 7) << 2;
                *(float4*)&Ks[row][d4] = *(const float4*)(ktb + row * DHH + d4);
                *(float4*)&Vs[row][d4] = *(const float4*)(vtb + row * DHH + d4);
            }
        }
        __syncthreads();

        // QK^T: this thread scores its row against keys c = 4*jj + qq
        float p[16];
        #pragma unroll
        for (int jj = 0; jj < 16; ++jj) {
            const int c = (jj << 2) + qq;
            float s0 = 0.f, s1 = 0.f, s2 = 0.f, s3 = 0.f;
            #pragma unroll
            for (int d4 = 0; d4 < 8; ++d4) {
                float4 kv = *(const float4*)&Ks[c][d4 << 2];
                s0 += qreg[d4*4+0] * kv.x;
                s1 += qreg[d4*4+1] * kv.y;
                s2 += qreg[d4*4+2] * kv.z;
                s3 += qreg[d4*4+3] * kv.w;
            }
            p[jj] = (s0 + s1) + (s2 + s3);
        }

        // online softmax across the quad (4 lanes own one row)
        float mloc = p[0];
        #pragma unroll
        for (int jj = 1; jj < 16; ++jj) mloc = fmaxf(mloc, p[jj]);
        mloc = fmaxf(mloc, __shfl_xor(mloc, 1, 4));
        mloc = fmaxf(mloc, __shfl_xor(mloc, 2, 4));
        const float m_new = fmaxf(m_run, mloc);
        const float resc  = __expf(m_run - m_new);
        m_run = m_new;
        float psum = 0.f;
        #pragma unroll
        for (int jj = 0; jj < 16; ++jj) {
            p[jj] = __expf(p[jj] - m_new);
            psum += p[jj];
        }
        l_run = l_run * resc + psum;
        #pragma unroll
        for (int c2 = 0; c2 < 32; ++c2) acc[c2] *= resc;

        // PV: accumulate all 32 output cols over this thread's 16 keys
        #pragma unroll
        for (int jj = 0; jj < 16; ++jj) {
            const int j = (jj << 2) + qq;
            const float pj = p[jj];
            #pragma unroll
            for (int d4 = 0; d4 < 8; ++d4) {
                float4 vv = *(const float4*)&Vs[j][d4 << 2];
                acc[d4*4+0] += pj * vv.x;
                acc[d4*4+1] += pj * vv.y;
                acc[d4*4+2] += pj * vv.z;
                acc[d4*4+3] += pj * vv.w;
            }
        }
    }

    // quad butterfly: every lane ends with the full 32-col row sum
    #pragma unroll
    for (int i = 0; i < 32; ++i) {
        acc[i] += __shfl_xor(acc[i], 1, 4);
        acc[i] += __shfl_xor(acc[i], 2, 4);
    }
    l_run += __shfl_xor(l_run, 1, 4);
    l_run += __shfl_xor(l_run, 2, 4);
    const float inv = 1.0f / l_run;

    // lane qq writes cols qq*8..qq*8+7 — static register indices via selects (no scratch)
    float ov[8];
    #pragma unroll
    for (int i = 0; i < 8; ++i) {
        const float pick = (qq == 0) ? acc[i] : (qq == 1) ? acc[8 + i]
                         : (qq == 2) ? acc[16 + i] : acc[24 + i];
        ov[i] = pick * inv;
    }
    const int sg = (qt << 6) + r;
    const int b  = bh >> 4;
    const int h  = bh & 15;
    float* op = mh + ((size_t)b * SS + sg) * DD + h * DHH + (qq << 3);
    float4 o0, o1;
    o0.x = ov[0]; o0.y = ov[1]; o0.z = ov[2]; o0.w = ov[3];
    o1.x = ov[4]; o1.y = ov[5]; o1.z = ov[6]; o1.w = ov[7];
    *(float4*)op = o0;
    *(float4*)(op + 4) = o1;
}

// ---------------- Output projection: y = mh @ Wo^T + bo ----------------
__global__ __launch_bounds__(256) void out_gemm_k(
    const float* __restrict__ mh, const float* __restrict__ Wo,
    const float* __restrict__ bo, float* __restrict__ y)
{
    __shared__ float As[16][68];
    __shared__ float Bs[16][68];
    const int t  = threadIdx.x;
    const int nt = blockIdx.x;   // 0..7
    const int mt = blockIdx.y;   // 0..127
    const int n0 = nt << 6, m0 = mt << 6;
    const int am = t >> 2;
    const int ak = (t & 3) << 2;
    const float* ap = mh + (size_t)(m0 + am) * DD + ak;
    const float* bp = Wo + (size_t)(n0 + am) * DD + ak;   // Wo rows = output cols (y = mh @ Wo^T)
    const int tm = (t >> 4) << 2;
    const int tn = (t & 15) << 2;
    float acc[4][4] = {{0.f,0.f,0.f,0.f},{0.f,0.f,0.f,0.f},{0.f,0.f,0.f,0.f},{0.f,0.f,0.f,0.f}};

    for (int k0 = 0; k0 < DD; k0 += 16) {
        float4 av  = *(const float4*)(ap + k0);
        float4 bv4 = *(const float4*)(bp + k0);
        __syncthreads();
        As[ak + 0][am] = av.x;
        As[ak + 1][am] = av.y;
        As[ak + 2][am] = av.z;
        As[ak + 3][am] = av.w;
        Bs[ak + 0][am] = bv4.x;
        Bs[ak + 1][am] = bv4.y;
        Bs[ak + 2][am] = bv4.z;
        Bs[ak + 3][am] = bv4.w;
        __syncthreads();
        #pragma unroll
        for (int kk = 0; kk < 16; ++kk) {
            float4 a4 = *(const float4*)&As[kk][tm];
            float4 b4 = *(const float4*)&Bs[kk][tn];
            fma16(acc, a4, b4);
        }
    }

    const float4 bb4 = *(const float4*)(bo + n0 + tn);
    #pragma unroll
    for (int i = 0; i < 4; ++i) {
        float4 o;
        o.x = acc[i][0] + bb4.x;
        o.y = acc[i][1] + bb4.y;
        o.z = acc[i][2] + bb4.z;
        o.w = acc[i][3] + bb4.w;
        *(float4*)(y + (size_t)(m0 + tm + i) * DD + n0 + tn) = o;
    }
}

extern "C" void kernel_launch(void* const* d_in, const int* in_sizes, int n_in,
                              void* d_out, int out_size, void* d_ws, size_t ws_size,
                              hipStream_t stream) {
    const float* x  = (const float*)d_in[0];
    const float* Wq = (const float*)d_in[1];
    const float* bq = (const float*)d_in[2];
    const float* Wk = (const float*)d_in[3];
    const float* bk = (const float*)d_in[4];
    const float* Wv = (const float*)d_in[5];
    const float* bv = (const float*)d_in[6];
    const float* Wo = (const float*)d_in[7];
    const float* bo = (const float*)d_in[8];
    float* y = (float*)d_out;

    float* ws = (float*)d_ws;
    const size_t qkv_elems = (size_t)BB * HH * SS * DHH;  // 4,194,304 each
    float* qbuf = ws;
    float* kbuf = ws + qkv_elems;
    float* vbuf = ws + 2 * qkv_elems;
    float* mhb  = ws + 3 * qkv_elems;   // [B,S,D] concat-head buffer; total ws use = 64 MiB

    qkv_gemm_k<<<dim3(24, 128), 256, 0, stream>>>(x, Wq, bq, Wk, bk, Wv, bv, qbuf, kbuf, vbuf);
    attn_k   <<<dim3(2048),     256, 0, stream>>>(qbuf, kbuf, vbuf, mhb);
    out_gemm_k<<<dim3(8, 128),  256, 0, stream>>>(mhb, Wo, bo, y);
}

// Round 2
// 196.063 us; speedup vs baseline: 4.9646x; 4.9646x over previous
//
#include <hip/hip_runtime.h>
#include <hip/hip_bf16.h>
#include <math.h>

#define BB 4
#define SS 2048
#define DD 512
#define HH 16
#define DHH 32
#define QSCALE 0.17677669529663687f

typedef __bf16 bf16x8  __attribute__((ext_vector_type(8)));
typedef __bf16 bf16x4v __attribute__((ext_vector_type(4)));
typedef float  f32x4   __attribute__((ext_vector_type(4)));

static __device__ __forceinline__ f32x4 mfma_16x16x32(bf16x8 a, bf16x8 b, f32x4 c) {
    return __builtin_amdgcn_mfma_f32_16x16x32_bf16(a, b, c, 0, 0, 0);
}

// ---------------- convert: x->bf16, W{q,k,v}->bf16 transposed [mat][H][DH][D], Wo->bf16 ----------
__global__ __launch_bounds__(256) void convert_k(
    const float* __restrict__ x,
    const float* __restrict__ Wq, const float* __restrict__ Wk, const float* __restrict__ Wv,
    const float* __restrict__ Wo,
    __bf16* __restrict__ xbf, __bf16* __restrict__ wt, __bf16* __restrict__ wob)
{
    const int bid = blockIdx.x;
    const int t = threadIdx.x;
    if (bid < 1024) {                       // x: 4,194,304 f32 = 1,048,576 float4
        for (int i = bid * 256 + t; i < 1048576; i += 1024 * 256) {
            float4 v = ((const float4*)x)[i];
            bf16x4v pk;
            pk[0] = (__bf16)v.x; pk[1] = (__bf16)v.y; pk[2] = (__bf16)v.z; pk[3] = (__bf16)v.w;
            ((bf16x4v*)xbf)[i] = pk;
        }
    } else if (bid < 1072) {                // W^T: 48 blocks (3 mats x 16 heads)
        const int id = bid - 1024;
        const int mat = id >> 4, h = id & 15;
        const float* W = (mat == 0) ? Wq : (mat == 1) ? Wk : Wv;
        const float sc = (mat == 0) ? QSCALE : 1.0f;
        const int dh = t >> 3, j = t & 7;
        const float* src = W + (size_t)h * DD * DHH + dh;       // W[h][d][dh], stride DHH
        __bf16* dst = wt + ((size_t)(mat * HH + h) * DHH + dh) * DD;
        for (int d = j * 64; d < j * 64 + 64; ++d)
            dst[d] = (__bf16)(src[(size_t)d * DHH] * sc);
    } else {                                // Wo: 262,144 f32 = 65,536 float4, 64 blocks
        const int id = bid - 1072;
        for (int i = id * 256 + t; i < 65536; i += 64 * 256) {
            float4 v = ((const float4*)Wo)[i];
            bf16x4v pk;
            pk[0] = (__bf16)v.x; pk[1] = (__bf16)v.y; pk[2] = (__bf16)v.z; pk[3] = (__bf16)v.w;
            ((bf16x4v*)wob)[i] = pk;
        }
    }
}

// ---------------- QKV projection, bf16 MFMA, no LDS ----------------
// Q,K out: [B,H,S,DH] bf16 (Q pre-scaled). V out: [B,H,DH,S] bf16 (transposed).
__global__ __launch_bounds__(512) void qkv_mfma_k(
    const __bf16* __restrict__ xbf, const __bf16* __restrict__ wt,
    const float* __restrict__ bq, const float* __restrict__ bk, const float* __restrict__ bv,
    __bf16* __restrict__ qb, __bf16* __restrict__ kb, __bf16* __restrict__ vtb)
{
    const int t = threadIdx.x;
    const int w = t >> 6, L = t & 63, lo = L & 15, g = L >> 4;
    const int wm = w & 3, wn = w >> 2;
    const int m_base = blockIdx.y * 256 + wm * 64;
    const int n_base = blockIdx.x * 128 + wn * 64;   // global col in [0,1536)
    const int mat = n_base >> 9;                     // uniform per block

    const __bf16* aptr[4];
    const __bf16* bptr[4];
    int headA[4], dhbA[4];
    #pragma unroll
    for (int fi = 0; fi < 4; ++fi)
        aptr[fi] = xbf + (size_t)(m_base + fi * 16 + lo) * DD + g * 8;
    #pragma unroll
    for (int fj = 0; fj < 4; ++fj) {
        const int nl = (n_base + fj * 16) & 511;
        headA[fj] = nl >> 5;
        dhbA[fj] = nl & 31;                          // 0 or 16
        bptr[fj] = wt + ((size_t)(mat * HH + headA[fj]) * DHH + dhbA[fj] + lo) * DD + g * 8;
    }

    f32x4 acc[4][4];
    #pragma unroll
    for (int fi = 0; fi < 4; ++fi)
        #pragma unroll
        for (int fj = 0; fj < 4; ++fj)
            acc[fi][fj] = f32x4{0.f, 0.f, 0.f, 0.f};

    for (int k0 = 0; k0 < DD; k0 += 32) {
        bf16x8 a[4], bfr[4];
        #pragma unroll
        for (int fi = 0; fi < 4; ++fi) a[fi] = *(const bf16x8*)(aptr[fi] + k0);
        #pragma unroll
        for (int fj = 0; fj < 4; ++fj) bfr[fj] = *(const bf16x8*)(bptr[fj] + k0);
        #pragma unroll
        for (int fi = 0; fi < 4; ++fi)
            #pragma unroll
            for (int fj = 0; fj < 4; ++fj)
                acc[fi][fj] = mfma_16x16x32(a[fi], bfr[fj], acc[fi][fj]);
    }

    const float* bias_p = (mat == 0) ? bq : (mat == 1) ? bk : bv;
    __bf16* outqk = (mat == 0) ? qb : kb;
    #pragma unroll
    for (int fj = 0; fj < 4; ++fj) {
        const int dh = dhbA[fj] + lo;
        float bias = bias_p[headA[fj] * DHH + dh];
        if (mat == 0) bias *= QSCALE;
        #pragma unroll
        for (int fi = 0; fi < 4; ++fi) {
            const int m0 = m_base + fi * 16 + g * 4;
            const int b = m0 >> 11, s0 = m0 & (SS - 1);
            if (mat < 2) {
                const size_t base = ((size_t)(b * HH + headA[fj]) * SS + s0) * DHH + dh;
                #pragma unroll
                for (int jj = 0; jj < 4; ++jj)
                    outqk[base + (size_t)jj * DHH] = (__bf16)(acc[fi][fj][jj] + bias);
            } else {
                bf16x4v pk;
                #pragma unroll
                for (int jj = 0; jj < 4; ++jj) pk[jj] = (__bf16)(acc[fi][fj][jj] + bias);
                *(bf16x4v*)(vtb + ((size_t)(b * HH + headA[fj]) * DHH + dh) * SS + s0) = pk;
            }
        }
    }
}

// ---------------- Flash attention, bf16 MFMA, swapped QK^T ----------------
__global__ __launch_bounds__(256) void attn_k(
    const __bf16* __restrict__ qb, const __bf16* __restrict__ kb,
    const __bf16* __restrict__ vtb, __bf16* __restrict__ mh)
{
    __shared__ __bf16 P[4][2][16][72];   // [wave][qfrag][qrow][key+pad] — wave-private
    const int t = threadIdx.x;
    const int w = t >> 6, L = t & 63, lo = L & 15, g = L >> 4;
    const int qt = blockIdx.x;           // 16 q-tiles of 128
    const int bh = blockIdx.y;           // 64
    const int b = bh >> 4, h = bh & 15;

    const size_t qkbase = (size_t)bh * SS * DHH;
    const int Rb = qt * 128 + w * 32;

    bf16x8 qf[2];
    #pragma unroll
    for (int q = 0; q < 2; ++q)
        qf[q] = *(const bf16x8*)(qb + qkbase + (size_t)(Rb + q * 16 + lo) * DHH + g * 8);

    f32x4 o[2][2];
    #pragma unroll
    for (int q = 0; q < 2; ++q)
        #pragma unroll
        for (int df = 0; df < 2; ++df) o[q][df] = f32x4{0.f, 0.f, 0.f, 0.f};
    float m_run[2] = {-INFINITY, -INFINITY};
    float l_run[2] = {0.f, 0.f};

    const __bf16* kbp = kb + qkbase;
    const __bf16* vbp = vtb + (size_t)bh * DHH * SS;

    for (int kt = 0; kt < SS / 64; ++kt) {
        // ---- QK^T (swapped: A=K tile, B=Q) -> S^T fragments ----
        bf16x8 kfr[4];
        #pragma unroll
        for (int kf = 0; kf < 4; ++kf)
            kfr[kf] = *(const bf16x8*)(kbp + (size_t)(kt * 64 + kf * 16 + lo) * DHH + g * 8);
        f32x4 s[2][4];
        #pragma unroll
        for (int q = 0; q < 2; ++q)
            #pragma unroll
            for (int kf = 0; kf < 4; ++kf)
                s[q][kf] = mfma_16x16x32(kfr[kf], qf[q], f32x4{0.f, 0.f, 0.f, 0.f});

        // ---- online softmax: lane owns q-row `lo` of qfrag q; keys in-lane + xor16/32 ----
        float resc_[2];
        #pragma unroll
        for (int q = 0; q < 2; ++q) {
            float mt_ = s[q][0][0];
            #pragma unroll
            for (int kf = 0; kf < 4; ++kf)
                #pragma unroll
                for (int jr = 0; jr < 4; ++jr) mt_ = fmaxf(mt_, s[q][kf][jr]);
            mt_ = fmaxf(mt_, __shfl_xor(mt_, 16));
            mt_ = fmaxf(mt_, __shfl_xor(mt_, 32));
            const float mnew = fmaxf(m_run[q], mt_);
            resc_[q] = __expf(m_run[q] - mnew);
            m_run[q] = mnew;
            float rs = 0.f;
            #pragma unroll
            for (int kf = 0; kf < 4; ++kf)
                #pragma unroll
                for (int jr = 0; jr < 4; ++jr) {
                    const float e = __expf(s[q][kf][jr] - mnew);
                    s[q][kf][jr] = e;
                    rs += e;
                }
            rs += __shfl_xor(rs, 16);
            rs += __shfl_xor(rs, 32);
            l_run[q] = l_run[q] * resc_[q] + rs;
        }

        // ---- rescale O (factor lives at lane (row&15); O rows are g*4+j) ----
        #pragma unroll
        for (int q = 0; q < 2; ++q) {
            #pragma unroll
            for (int j = 0; j < 4; ++j) {
                const float rr = __shfl(resc_[q], g * 4 + j);
                o[q][0][j] *= rr;
                o[q][1][j] *= rr;
            }
        }

        // ---- P -> LDS (bf16, A-layout friendly), wave-private ----
        #pragma unroll
        for (int q = 0; q < 2; ++q)
            #pragma unroll
            for (int kf = 0; kf < 4; ++kf) {
                bf16x4v pk;
                #pragma unroll
                for (int jr = 0; jr < 4; ++jr) pk[jr] = (__bf16)s[q][kf][jr];
                *(bf16x4v*)&P[w][q][lo][kf * 16 + g * 4] = pk;
            }

        // ---- PV: A = P (from LDS), B = V^T direct global ----
        bf16x8 vfr[2][2];
        #pragma unroll
        for (int df = 0; df < 2; ++df)
            #pragma unroll
            for (int ks = 0; ks < 2; ++ks)
                vfr[df][ks] = *(const bf16x8*)(vbp + (size_t)(df * 16 + lo) * SS
                                               + kt * 64 + ks * 32 + g * 8);
        #pragma unroll
        for (int q = 0; q < 2; ++q) {
            bf16x8 pa[2];
            #pragma unroll
            for (int ks = 0; ks < 2; ++ks)
                pa[ks] = *(const bf16x8*)&P[w][q][lo][ks * 32 + g * 8];
            #pragma unroll
            for (int df = 0; df < 2; ++df)
                #pragma unroll
                for (int ks = 0; ks < 2; ++ks)
                    o[q][df] = mfma_16x16x32(pa[ks], vfr[df][ks], o[q][df]);
        }
    }

    // ---- finalize: divide by l (redistribute like rescale), store bf16 concat-head ----
    #pragma unroll
    for (int q = 0; q < 2; ++q) {
        const float inv = 1.0f / l_run[q];
        float li[4];
        #pragma unroll
        for (int j = 0; j < 4; ++j) li[j] = __shfl(inv, g * 4 + j);
        #pragma unroll
        for (int df = 0; df < 2; ++df) {
            #pragma unroll
            for (int j = 0; j < 4; ++j) {
                const int srow = Rb + q * 16 + g * 4 + j;
                mh[((size_t)b * SS + srow) * DD + h * DHH + df * 16 + lo] =
                    (__bf16)(o[q][df][j] * li[j]);
            }
        }
    }
}

// ---------------- Output projection: y = mh @ Wo^T + bo (f32 out) ----------------
__global__ __launch_bounds__(256) void oproj_k(
    const __bf16* __restrict__ mh, const __bf16* __restrict__ wob,
    const float* __restrict__ bo, float* __restrict__ y)
{
    const int t = threadIdx.x;
    const int w = t >> 6, L = t & 63, lo = L & 15, g = L >> 4;
    const int wm = w & 1, wn = w >> 1;
    const int m_base = blockIdx.y * 128 + wm * 64;
    const int n_base = blockIdx.x * 128 + wn * 64;

    const __bf16* aptr[4];
    const __bf16* bptr[4];
    #pragma unroll
    for (int fi = 0; fi < 4; ++fi)
        aptr[fi] = mh + (size_t)(m_base + fi * 16 + lo) * DD + g * 8;
    #pragma unroll
    for (int fj = 0; fj < 4; ++fj)
        bptr[fj] = wob + (size_t)(n_base + fj * 16 + lo) * DD + g * 8;

    f32x4 acc[4][4];
    #pragma unroll
    for (int fi = 0; fi < 4; ++fi)
        #pragma unroll
        for (int fj = 0; fj < 4; ++fj)
            acc[fi][fj] = f32x4{0.f, 0.f, 0.f, 0.f};

    for (int k0 = 0; k0 < DD; k0 += 32) {
        bf16x8 a[4], bfr[4];
        #pragma unroll
        for (int fi = 0; fi < 4; ++fi) a[fi] = *(const bf16x8*)(aptr[fi] + k0);
        #pragma unroll
        for (int fj = 0; fj < 4; ++fj) bfr[fj] = *(const bf16x8*)(bptr[fj] + k0);
        #pragma unroll
        for (int fi = 0; fi < 4; ++fi)
            #pragma unroll
            for (int fj = 0; fj < 4; ++fj)
                acc[fi][fj] = mfma_16x16x32(a[fi], bfr[fj], acc[fi][fj]);
    }

    #pragma unroll
    for (int fj = 0; fj < 4; ++fj) {
        const int n = n_base + fj * 16 + lo;
        const float bias = bo[n];
        #pragma unroll
        for (int fi = 0; fi < 4; ++fi) {
            const int m0 = m_base + fi * 16 + g * 4;
            #pragma unroll
            for (int jj = 0; jj < 4; ++jj)
                y[(size_t)(m0 + jj) * DD + n] = acc[fi][fj][jj] + bias;
        }
    }
}

extern "C" void kernel_launch(void* const* d_in, const int* in_sizes, int n_in,
                              void* d_out, int out_size, void* d_ws, size_t ws_size,
                              hipStream_t stream) {
    const float* x  = (const float*)d_in[0];
    const float* Wq = (const float*)d_in[1];
    const float* bq = (const float*)d_in[2];
    const float* Wk = (const float*)d_in[3];
    const float* bk = (const float*)d_in[4];
    const float* Wv = (const float*)d_in[5];
    const float* bv = (const float*)d_in[6];
    const float* Wo = (const float*)d_in[7];
    const float* bo = (const float*)d_in[8];
    float* y = (float*)d_out;

    char* wsb = (char*)d_ws;
    __bf16* xbf  = (__bf16*)(wsb);                  //  8,388,608 B
    __bf16* qbuf = (__bf16*)(wsb +  8388608);       //  8,388,608 B
    __bf16* kbuf = (__bf16*)(wsb + 16777216);       //  8,388,608 B
    __bf16* vtb  = (__bf16*)(wsb + 25165824);       //  8,388,608 B
    __bf16* mhb  = (__bf16*)(wsb + 33554432);       //  8,388,608 B
    __bf16* wt   = (__bf16*)(wsb + 41943040);       //  1,572,864 B
    __bf16* wob  = (__bf16*)(wsb + 43515904);       //    524,288 B  (end 44,040,192)

    convert_k <<<1136, 256, 0, stream>>>(x, Wq, Wk, Wv, Wo, xbf, wt, wob);
    qkv_mfma_k<<<dim3(12, 32), 512, 0, stream>>>(xbf, wt, bq, bk, bv, qbuf, kbuf, vtb);
    attn_k    <<<dim3(16, 64), 256, 0, stream>>>(qbuf, kbuf, vtb, mhb);
    oproj_k   <<<dim3(4, 64), 256, 0, stream>>>(mhb, wob, bo, y);
}